// Round 1
// baseline (279.100 us; speedup 1.0000x reference)
//
#include <hip/hip_runtime.h>
#include <math.h>

// Problem constants (B=4, N=4096, d_in=d_g=1024, K=512)
constexpr int D_IN = 1024;
constexpr int KCB  = 512;
constexpr int BM   = 32;     // rows per block
constexpr int DC   = 32;     // d-chunk staged in LDS
constexpr int ZSTR = BM + 4; // padded row stride for zs (36 words -> 144B, 16B aligned)

// ---------------------------------------------------------------------------
// Kernel A: normalize codebook rows and write TRANSPOSED CfT[d][k] to ws.
// 512 blocks x 256 threads; one block per codebook row.
// ---------------------------------------------------------------------------
__global__ __launch_bounds__(256)
void normalize_codebook(const float* __restrict__ cb, float* __restrict__ cft) {
    const int k   = blockIdx.x;   // 0..511
    const int tid = threadIdx.x;  // 0..255
    const float4 v = reinterpret_cast<const float4*>(cb + (size_t)k * D_IN)[tid];
    float ss = v.x * v.x + v.y * v.y + v.z * v.z + v.w * v.w;
#pragma unroll
    for (int off = 32; off > 0; off >>= 1) ss += __shfl_down(ss, off);
    __shared__ float wss[4];
    if ((tid & 63) == 0) wss[tid >> 6] = ss;
    __syncthreads();
    const float tot   = wss[0] + wss[1] + wss[2] + wss[3];
    const float scale = 1.0f / fmaxf(sqrtf(tot), 1e-12f);
    const int d0 = tid * 4;
    cft[(size_t)(d0 + 0) * KCB + k] = v.x * scale;
    cft[(size_t)(d0 + 1) * KCB + k] = v.y * scale;
    cft[(size_t)(d0 + 2) * KCB + k] = v.z * scale;
    cft[(size_t)(d0 + 3) * KCB + k] = v.w * scale;
}

// ---------------------------------------------------------------------------
// Kernel B: fused GEMM(z, CfT) -> per-row argmax -> out = target*(1+E[best]).
// Block: 256 threads = kg(0..31) x rg(0..7). Each thread: 4 rows x 16 k.
// k per thread: kg*2 + m + 64*jj  (m in {0,1}, jj in 0..7) -> covers all 512.
// ---------------------------------------------------------------------------
__global__ __launch_bounds__(256, 2)
void vq_main(const float* __restrict__ z, const float* __restrict__ tgt,
             const float* __restrict__ cft, const float* __restrict__ E,
             float* __restrict__ out) {
    __shared__ float zs[DC * ZSTR];   // z transposed: [d][row], padded
    __shared__ float cs[DC * KCB];    // c transposed: [d][k]  (64 KiB)
    __shared__ int   bestk_s[BM];

    const int tid = threadIdx.x;
    const int r0  = blockIdx.x * BM;
    const int kg  = tid & 31;
    const int rg  = tid >> 5;  // 0..7

    float acc[4][16];
#pragma unroll
    for (int i = 0; i < 4; ++i)
#pragma unroll
        for (int j = 0; j < 16; ++j) acc[i][j] = 0.0f;

    for (int dc = 0; dc < D_IN; dc += DC) {
        if (dc) __syncthreads();
        // --- stage z tile (32 rows x 32 d), transposed into zs[d][row] ---
        {
            const int row = tid >> 3;          // 0..31
            const int dg  = tid & 7;           // 0..7
            const float4 v = *reinterpret_cast<const float4*>(
                z + (size_t)(r0 + row) * D_IN + dc + dg * 4);
            zs[(dg * 4 + 0) * ZSTR + row] = v.x;
            zs[(dg * 4 + 1) * ZSTR + row] = v.y;
            zs[(dg * 4 + 2) * ZSTR + row] = v.z;
            zs[(dg * 4 + 3) * ZSTR + row] = v.w;
        }
        // --- stage c tile (32 d x 512 k), already transposed in cft ---
#pragma unroll
        for (int t = 0; t < 16; ++t) {
            const int idx = tid + 256 * t;     // 0..4095
            const int d   = idx >> 7;          // 0..31
            const int kq  = idx & 127;         // 0..127
            const float4 v = *reinterpret_cast<const float4*>(
                cft + (size_t)(dc + d) * KCB + kq * 4);
            *reinterpret_cast<float4*>(&cs[d * KCB + kq * 4]) = v;
        }
        __syncthreads();
        // --- accumulate ---
#pragma unroll 2
        for (int d = 0; d < DC; ++d) {
            float zr[4];
            {
                const float4 a = *reinterpret_cast<const float4*>(&zs[d * ZSTR + rg * 4]);
                zr[0] = a.x; zr[1] = a.y; zr[2] = a.z; zr[3] = a.w;
            }
            float ck[16];
#pragma unroll
            for (int jj = 0; jj < 8; ++jj) {
                const float2 c2 = *reinterpret_cast<const float2*>(
                    &cs[d * KCB + kg * 2 + 64 * jj]);
                ck[2 * jj]     = c2.x;
                ck[2 * jj + 1] = c2.y;
            }
#pragma unroll
            for (int i = 0; i < 4; ++i)
#pragma unroll
                for (int j = 0; j < 16; ++j)
                    acc[i][j] = fmaf(zr[i], ck[j], acc[i][j]);
        }
    }

    // --- per-thread argmax over its 16 k, per row (increasing k order) ---
    float bestv[4];
    int   besti[4];
#pragma unroll
    for (int i = 0; i < 4; ++i) {
        float bv = acc[i][0];
        int   bi = kg * 2;
#pragma unroll
        for (int jj = 0; jj < 8; ++jj)
#pragma unroll
            for (int m = 0; m < 2; ++m) {
                if (jj == 0 && m == 0) continue;
                const float v = acc[i][2 * jj + m];
                const int   kk = kg * 2 + 64 * jj + m;
                if (v > bv) { bv = v; bi = kk; }  // strict >: earliest k wins ties
            }
        bestv[i] = bv; besti[i] = bi;
    }

    // --- cross-thread reduce (32 kg lanes per row) via LDS ---
    __syncthreads();
    float* redv = cs;                       // [BM][32] floats
    int*   redi = (int*)(cs + BM * 32);     // [BM][32] ints
#pragma unroll
    for (int i = 0; i < 4; ++i) {
        const int row = rg * 4 + i;
        redv[row * 32 + kg] = bestv[i];
        redi[row * 32 + kg] = besti[i];
    }
    __syncthreads();
    if (tid < BM) {
        float bv = redv[tid * 32];
        int   bi = redi[tid * 32];
        for (int t = 1; t < 32; ++t) {
            const float v  = redv[tid * 32 + t];
            const int   ix = redi[tid * 32 + t];
            if (v > bv || (v == bv && ix < bi)) { bv = v; bi = ix; }
        }
        bestk_s[tid] = bi;
    }
    __syncthreads();

    // --- epilogue: out = target * (1 + E[best]) ---
    for (int t = 0; t < BM; ++t) {
        const int bi = bestk_s[t];
        const float4 tv = *reinterpret_cast<const float4*>(
            tgt + (size_t)(r0 + t) * D_IN + tid * 4);
        const float4 ev = *reinterpret_cast<const float4*>(
            E + (size_t)bi * D_IN + tid * 4);
        float4 o;
        o.x = tv.x * (1.0f + ev.x);
        o.y = tv.y * (1.0f + ev.y);
        o.z = tv.z * (1.0f + ev.z);
        o.w = tv.w * (1.0f + ev.w);
        *reinterpret_cast<float4*>(out + (size_t)(r0 + t) * D_IN + tid * 4) = o;
    }
}

extern "C" void kernel_launch(void* const* d_in, const int* in_sizes, int n_in,
                              void* d_out, int out_size, void* d_ws, size_t ws_size,
                              hipStream_t stream) {
    const float* z        = (const float*)d_in[0];  // [B,N,1024]
    const float* target   = (const float*)d_in[1];  // [B,N,1024]
    const float* codebook = (const float*)d_in[2];  // [512,1024]
    const float* E        = (const float*)d_in[3];  // [512,1024]
    float* out = (float*)d_out;
    float* cft = (float*)d_ws;                      // 1024*512*4 = 2 MiB

    const int rows = in_sizes[0] / D_IN;            // 16384
    hipLaunchKernelGGL(normalize_codebook, dim3(KCB), dim3(256), 0, stream,
                       codebook, cft);
    hipLaunchKernelGGL(vq_main, dim3(rows / BM), dim3(256), 0, stream,
                       z, target, cft, E, out);
}